// Round 6
// baseline (516.888 us; speedup 1.0000x reference)
//
#include <hip/hip_runtime.h>
#include <hip/hip_bf16.h>
#include <hip/hip_cooperative_groups.h>

namespace cg = cooperative_groups;

#define NN 6144
#define IN_DIM 256
#define HID 64
#define HEADS 4
#define LAT 32
#define CAP 192
#define ALPHA 0.2f
#define GEMM_BLOCKS 384                  // (NN/64) * HEADS
#define ZTILES ((NN / 64) * (NN / 64))   // 9216

typedef __attribute__((ext_vector_type(8))) short bf16x8;
typedef __attribute__((ext_vector_type(4))) float f32x4;

__device__ __forceinline__ float elu_f(float v)   { return v > 0.f ? v : expm1f(v); }
__device__ __forceinline__ float lrelu_f(float v) { return v > 0.f ? v : ALPHA * v; }

__device__ __forceinline__ void split_bf16(float v, unsigned short& hi, unsigned short& lo) {
    unsigned u = __builtin_bit_cast(unsigned, v);
    hi = (unsigned short)(u >> 16);
    float vh = __builtin_bit_cast(float, u & 0xFFFF0000u);
    float rl = v - vh;                       // exact
    lo = (unsigned short)(__builtin_bit_cast(unsigned, rl) >> 16);
}

// ===================== phase bodies (shared by mega + fallback) =====================

__device__ void phase_gemm1(int bid, int t, char* smraw,
                            const float* __restrict__ x, const float* __restrict__ Wheads,
                            const float* __restrict__ aheads,
                            float* __restrict__ Wh, float* __restrict__ es, float* __restrict__ ed) {
    float (*As)[64] = (float(*)[64])smraw;            // [16][64] 4KB
    float (*Bs)[64] = (float(*)[64])(smraw + 4096);   // [16][64] 4KB
    int head = bid & 3, m0 = (bid >> 2) * 64;
    const float* Wc = Wheads + (size_t)head * IN_DIM * HID;
    int ty = t >> 4, tx = t & 15;
    float acc[4][4] = {};
    for (int k0 = 0; k0 < IN_DIM; k0 += 16) {
        {
            int row = t >> 2, k4 = (t & 3) * 4;
            float4 v = *(const float4*)(x + (size_t)(m0 + row) * IN_DIM + k0 + k4);
            As[k4 + 0][row] = v.x; As[k4 + 1][row] = v.y;
            As[k4 + 2][row] = v.z; As[k4 + 3][row] = v.w;
            int kk = t >> 4, n4 = (t & 15) * 4;
            *(float4*)&Bs[kk][n4] = *(const float4*)(Wc + (size_t)(k0 + kk) * HID + n4);
        }
        __syncthreads();
        #pragma unroll
        for (int k = 0; k < 16; ++k) {
            float4 av = *(float4*)&As[k][ty * 4];
            float4 bv = *(float4*)&Bs[k][tx * 4];
            float ar[4] = {av.x, av.y, av.z, av.w};
            float br[4] = {bv.x, bv.y, bv.z, bv.w};
            #pragma unroll
            for (int i = 0; i < 4; ++i)
                #pragma unroll
                for (int j = 0; j < 4; ++j)
                    acc[i][j] = fmaf(ar[i], br[j], acc[i][j]);
        }
        __syncthreads();
    }
    #pragma unroll
    for (int i = 0; i < 4; ++i) {
        float4 o = make_float4(acc[i][0], acc[i][1], acc[i][2], acc[i][3]);
        *(float4*)(Wh + (size_t)(m0 + ty * 4 + i) * (HEADS * HID) + head * HID + tx * 4) = o;
    }
    float4 a1v = *(const float4*)(aheads + head * 2 * HID + tx * 4);
    float4 a2v = *(const float4*)(aheads + head * 2 * HID + HID + tx * 4);
    #pragma unroll
    for (int i = 0; i < 4; ++i) {
        float p1 = acc[i][0] * a1v.x + acc[i][1] * a1v.y + acc[i][2] * a1v.z + acc[i][3] * a1v.w;
        float p2 = acc[i][0] * a2v.x + acc[i][1] * a2v.y + acc[i][2] * a2v.z + acc[i][3] * a2v.w;
        #pragma unroll
        for (int off = 8; off; off >>= 1) {
            p1 += __shfl_down(p1, off, 16);
            p2 += __shfl_down(p2, off, 16);
        }
        if (tx == 0) {
            es[head * NN + m0 + ty * 4 + i] = p1;
            ed[head * NN + m0 + ty * 4 + i] = p2;
        }
    }
}

__device__ void phase_scan(int row, int t, char* smraw,
                           const float* __restrict__ A,
                           int* __restrict__ nbr, int* __restrict__ cnt) {
    int* lcnt = (int*)smraw;
    const float4* Arow = (const float4*)(A + (size_t)row * NN);
    if (t == 0) *lcnt = 0;
    __syncthreads();
    int* my = nbr + (size_t)row * CAP;
    #pragma unroll
    for (int it = 0; it < NN / 4 / 256; ++it) {
        int idx4 = it * 256 + t;
        float4 v = Arow[idx4];
        int base = idx4 * 4;
        if (v.x != 0.f) { int p = atomicAdd(lcnt, 1); if (p < CAP) my[p] = base; }
        if (v.y != 0.f) { int p = atomicAdd(lcnt, 1); if (p < CAP) my[p] = base + 1; }
        if (v.z != 0.f) { int p = atomicAdd(lcnt, 1); if (p < CAP) my[p] = base + 2; }
        if (v.w != 0.f) { int p = atomicAdd(lcnt, 1); if (p < CAP) my[p] = base + 3; }
    }
    __syncthreads();
    if (t == 0) cnt[row] = *lcnt < CAP ? *lcnt : CAP;
}

__device__ void phase_attn1g2(int i, int t, char* smraw,
                              const int* __restrict__ nbr, const int* __restrict__ cnt,
                              const float* __restrict__ es, const float* __restrict__ ed,
                              const float* __restrict__ Wh,
                              const float* __restrict__ Wout, const float* __restrict__ aout,
                              float* __restrict__ Wh2,
                              float* __restrict__ es2, float* __restrict__ ed2) {
    int h = t >> 6, l = t & 63;
    int* col           = (int*)smraw;                          // [CAP]      768B
    float (*att)[CAP]  = (float(*)[CAP])(smraw + 768);         // [4][CAP]   3072B
    float* hrow        = (float*)(smraw + 768 + 3072);         // [256]      1024B
    float (*part)[LAT] = (float(*)[LAT])(smraw + 768 + 3072 + 1024); // [8][32] 1024B
    int c = cnt[i];
    float hval;
    if (c == 0) {
        float s = 0.f;
        for (int r = 0; r < NN; ++r) s += Wh[(size_t)r * (HEADS * HID) + h * HID + l];
        hval = elu_f(s * (1.0f / NN));
    } else {
        const int* nb = nbr + (size_t)i * CAP;
        float esi = es[h * NN + i];
        float m = -3.0e38f;
        for (int j = l; j < c; j += 64) {
            int cj = nb[j];
            if (h == 0) col[j] = cj;
            float e = lrelu_f(esi + ed[h * NN + cj]);
            att[h][j] = e;
            m = fmaxf(m, e);
        }
        #pragma unroll
        for (int off = 32; off; off >>= 1) m = fmaxf(m, __shfl_down(m, off));
        m = __shfl(m, 0);
        float s = 0.f;
        for (int j = l; j < c; j += 64) {
            float p = __expf(att[h][j] - m);
            att[h][j] = p;
            s += p;
        }
        #pragma unroll
        for (int off = 32; off; off >>= 1) s += __shfl_down(s, off);
        s = __shfl(s, 0);
        __syncthreads();
        float inv = 1.0f / s;
        const float* WhH = Wh + h * HID + l;
        float acc0 = 0.f, acc1 = 0.f, acc2 = 0.f, acc3 = 0.f;
        int j = 0;
        for (; j + 4 <= c; j += 4) {
            acc0 = fmaf(att[h][j + 0], WhH[(size_t)col[j + 0] * (HEADS * HID)], acc0);
            acc1 = fmaf(att[h][j + 1], WhH[(size_t)col[j + 1] * (HEADS * HID)], acc1);
            acc2 = fmaf(att[h][j + 2], WhH[(size_t)col[j + 2] * (HEADS * HID)], acc2);
            acc3 = fmaf(att[h][j + 3], WhH[(size_t)col[j + 3] * (HEADS * HID)], acc3);
        }
        for (; j < c; ++j)
            acc0 = fmaf(att[h][j], WhH[(size_t)col[j] * (HEADS * HID)], acc0);
        hval = elu_f(((acc0 + acc1) + (acc2 + acc3)) * inv);
    }
    hrow[h * HID + l] = hval;
    __syncthreads();
    {
        int half = l >> 5, cc = l & 31;
        int tbase = h * HID + half * 32;
        float p = 0.f;
        #pragma unroll 8
        for (int tt = 0; tt < 32; ++tt)
            p = fmaf(hrow[tbase + tt], Wout[(tbase + tt) * LAT + cc], p);
        part[h * 2 + half][cc] = p;
    }
    __syncthreads();
    if (t < 32) {
        float acc = 0.f;
        #pragma unroll
        for (int w = 0; w < 8; ++w) acc += part[w][t];
        Wh2[(size_t)i * LAT + t] = acc;
        float p1 = acc * aout[t], p2 = acc * aout[LAT + t];
        #pragma unroll
        for (int off = 16; off; off >>= 1) {
            p1 += __shfl_down(p1, off, 32);
            p2 += __shfl_down(p2, off, 32);
        }
        if (t == 0) { es2[i] = p1; ed2[i] = p2; }
    }
}

__device__ void phase_attn2(int g, int t, char* smraw,
                            const int* __restrict__ nbr, const int* __restrict__ cnt,
                            const float* __restrict__ es2, const float* __restrict__ ed2,
                            const float* __restrict__ Wh2,
                            unsigned short* __restrict__ zh, unsigned short* __restrict__ zl) {
    int w = t >> 6, l = t & 63;
    float (*att)[CAP] = (float(*)[CAP])smraw;                // [4][CAP] 3072B
    int (*col)[CAP]   = (int(*)[CAP])(smraw + 3072);         // [4][CAP] 3072B
    int i = g * 4 + w;
    int c = cnt[i];
    if (c == 0) {
        if (l < LAT) {
            float s = 0.f;
            for (int r = 0; r < NN; ++r) s += Wh2[(size_t)r * LAT + l];
            unsigned short hi, lo;
            split_bf16(elu_f(s * (1.0f / NN)), hi, lo);
            zh[(size_t)i * LAT + l] = hi;
            zl[(size_t)i * LAT + l] = lo;
        }
        return;
    }
    float esi = es2[i];
    const int* nb = nbr + (size_t)i * CAP;
    float m = -3.0e38f;
    for (int j = l; j < c; j += 64) {
        int cj = nb[j];
        col[w][j] = cj;
        float e = lrelu_f(esi + ed2[cj]);
        att[w][j] = e;
        m = fmaxf(m, e);
    }
    #pragma unroll
    for (int off = 32; off; off >>= 1) m = fmaxf(m, __shfl_down(m, off));
    m = __shfl(m, 0);
    float s = 0.f;
    for (int j = l; j < c; j += 64) {
        float p = __expf(att[w][j] - m);
        att[w][j] = p;
        s += p;
    }
    #pragma unroll
    for (int off = 32; off; off >>= 1) s += __shfl_down(s, off);
    s = __shfl(s, 0);
    if (l < LAT) {
        float inv = 1.0f / s;
        float acc0 = 0.f, acc1 = 0.f, acc2 = 0.f, acc3 = 0.f;
        int j = 0;
        for (; j + 4 <= c; j += 4) {
            acc0 = fmaf(att[w][j + 0], Wh2[(size_t)col[w][j + 0] * LAT + l], acc0);
            acc1 = fmaf(att[w][j + 1], Wh2[(size_t)col[w][j + 1] * LAT + l], acc1);
            acc2 = fmaf(att[w][j + 2], Wh2[(size_t)col[w][j + 2] * LAT + l], acc2);
            acc3 = fmaf(att[w][j + 3], Wh2[(size_t)col[w][j + 3] * LAT + l], acc3);
        }
        for (; j < c; ++j)
            acc0 = fmaf(att[w][j], Wh2[(size_t)col[w][j] * LAT + l], acc0);
        unsigned short hi, lo;
        split_bf16(elu_f(((acc0 + acc1) + (acc2 + acc3)) * inv), hi, lo);
        zh[(size_t)i * LAT + l] = hi;
        zl[(size_t)i * LAT + l] = lo;
    }
}

__device__ void phase_zzt(int tile, int t,
                          const unsigned short* __restrict__ zh,
                          const unsigned short* __restrict__ zl,
                          float* __restrict__ out) {
    int w = t >> 6, l = t & 63;
    int r = l & 15, kg = (l >> 4) * 8;
    int by = tile / (NN / 64), bx = tile % (NN / 64);
    int m0 = by * 64 + w * 16;
    int n0 = bx * 64;
    bf16x8 ah = *(const bf16x8*)(zh + (size_t)(m0 + r) * LAT + kg);
    bf16x8 al = *(const bf16x8*)(zl + (size_t)(m0 + r) * LAT + kg);
    #pragma unroll
    for (int j = 0; j < 4; ++j) {
        int nb = n0 + j * 16;
        bf16x8 bh = *(const bf16x8*)(zh + (size_t)(nb + r) * LAT + kg);
        bf16x8 bl = *(const bf16x8*)(zl + (size_t)(nb + r) * LAT + kg);
        f32x4 acc = {0.f, 0.f, 0.f, 0.f};
        acc = __builtin_amdgcn_mfma_f32_16x16x32_bf16(ah, bh, acc, 0, 0, 0);
        acc = __builtin_amdgcn_mfma_f32_16x16x32_bf16(ah, bl, acc, 0, 0, 0);
        acc = __builtin_amdgcn_mfma_f32_16x16x32_bf16(al, bh, acc, 0, 0, 0);
        #pragma unroll
        for (int rr = 0; rr < 4; ++rr) {
            int row = m0 + (l >> 4) * 4 + rr;
            int colo = nb + (l & 15);
            out[(size_t)row * NN + colo] = 1.0f / (1.0f + __expf(-acc[rr]));
        }
    }
}

// ===================== cooperative mega-kernel =====================
__global__ __launch_bounds__(256, 4) void k_mega(
        const float* __restrict__ A, const float* __restrict__ x,
        const float* __restrict__ Wheads, const float* __restrict__ aheads,
        const float* __restrict__ Wout, const float* __restrict__ aout,
        int* __restrict__ nbr, int* __restrict__ cnt,
        float* __restrict__ Wh, float* __restrict__ es, float* __restrict__ ed,
        float* __restrict__ Wh2, float* __restrict__ es2, float* __restrict__ ed2,
        unsigned short* __restrict__ zh, unsigned short* __restrict__ zl,
        float* __restrict__ out) {
    __shared__ __align__(16) char smraw[8192];
    cg::grid_group grid = cg::this_grid();
    int t = threadIdx.x;
    int nbk = gridDim.x;

    for (int bid = blockIdx.x; bid < GEMM_BLOCKS + NN; bid += nbk) {
        __syncthreads();
        if (bid < GEMM_BLOCKS) phase_gemm1(bid, t, smraw, x, Wheads, aheads, Wh, es, ed);
        else                   phase_scan(bid - GEMM_BLOCKS, t, smraw, A, nbr, cnt);
    }
    __threadfence();
    grid.sync();

    for (int i = blockIdx.x; i < NN; i += nbk) {
        __syncthreads();
        phase_attn1g2(i, t, smraw, nbr, cnt, es, ed, Wh, Wout, aout, Wh2, es2, ed2);
    }
    __threadfence();
    grid.sync();

    for (int g = blockIdx.x; g < NN / 4; g += nbk)
        phase_attn2(g, t, smraw, nbr, cnt, es2, ed2, Wh2, zh, zl);
    __threadfence();
    grid.sync();

    for (int tile = blockIdx.x; tile < ZTILES; tile += nbk)
        phase_zzt(tile, t, zh, zl, out);
}

// ===================== fallback kernels (R4-identical behavior) =====================
__global__ __launch_bounds__(256) void k_pre(const float* __restrict__ A, const float* __restrict__ x,
                                             const float* __restrict__ Wheads, const float* __restrict__ aheads,
                                             int* __restrict__ nbr, int* __restrict__ cnt,
                                             float* __restrict__ Wh, float* __restrict__ es, float* __restrict__ ed) {
    __shared__ __align__(16) char smraw[8192];
    if (blockIdx.x < GEMM_BLOCKS) phase_gemm1(blockIdx.x, threadIdx.x, smraw, x, Wheads, aheads, Wh, es, ed);
    else                          phase_scan(blockIdx.x - GEMM_BLOCKS, threadIdx.x, smraw, A, nbr, cnt);
}
__global__ __launch_bounds__(256) void k_attn1g2(const int* __restrict__ nbr, const int* __restrict__ cnt,
                                                 const float* __restrict__ es, const float* __restrict__ ed,
                                                 const float* __restrict__ Wh,
                                                 const float* __restrict__ Wout, const float* __restrict__ aout,
                                                 float* __restrict__ Wh2, float* __restrict__ es2, float* __restrict__ ed2) {
    __shared__ __align__(16) char smraw[8192];
    phase_attn1g2(blockIdx.x, threadIdx.x, smraw, nbr, cnt, es, ed, Wh, Wout, aout, Wh2, es2, ed2);
}
__global__ __launch_bounds__(256) void k_attn2(const int* __restrict__ nbr, const int* __restrict__ cnt,
                                               const float* __restrict__ es2, const float* __restrict__ ed2,
                                               const float* __restrict__ Wh2,
                                               unsigned short* __restrict__ zh, unsigned short* __restrict__ zl) {
    __shared__ __align__(16) char smraw[8192];
    phase_attn2(blockIdx.x, threadIdx.x, smraw, nbr, cnt, es2, ed2, Wh2, zh, zl);
}
__global__ __launch_bounds__(256) void k_zzt(const unsigned short* __restrict__ zh,
                                             const unsigned short* __restrict__ zl,
                                             float* __restrict__ out) {
    phase_zzt(blockIdx.x, threadIdx.x, zh, zl, out);
}

extern "C" void kernel_launch(void* const* d_in, const int* in_sizes, int n_in,
                              void* d_out, int out_size, void* d_ws, size_t ws_size,
                              hipStream_t stream) {
    const float* x      = (const float*)d_in[0];
    const float* A      = (const float*)d_in[1];
    const float* Wheads = (const float*)d_in[2];
    const float* aheads = (const float*)d_in[3];
    const float* Wout   = (const float*)d_in[4];
    const float* aout   = (const float*)d_in[5];
    float* out = (float*)d_out;

    char* ws = (char*)d_ws;
    size_t o = 0;
    auto alloc = [&](size_t bytes) { void* p = ws + o; o += (bytes + 255) & ~(size_t)255; return p; };
    int*   nbr   = (int*)  alloc((size_t)NN * CAP * 4);
    int*   cnt   = (int*)  alloc((size_t)NN * 4);
    float* Wh    = (float*)alloc((size_t)NN * HEADS * HID * 4);
    float* es    = (float*)alloc((size_t)HEADS * NN * 4);
    float* ed    = (float*)alloc((size_t)HEADS * NN * 4);
    float* Wh2   = (float*)alloc((size_t)NN * LAT * 4);
    float* es2   = (float*)alloc((size_t)NN * 4);
    float* ed2   = (float*)alloc((size_t)NN * 4);
    unsigned short* zh = (unsigned short*)alloc((size_t)NN * LAT * 2);
    unsigned short* zl = (unsigned short*)alloc((size_t)NN * LAT * 2);

    // deterministic occupancy-clamped cooperative launch; fallback to 4-kernel path
    int maxB = 0;
    hipError_t oe = hipOccupancyMaxActiveBlocksPerMultiprocessor(&maxB, k_mega, 256, 0);
    hipError_t le = hipErrorUnknown;
    if (oe == hipSuccess && maxB > 0) {
        int gridB = maxB * 256;                    // 256 CUs on MI355X
        if (gridB > ZTILES) gridB = ZTILES;
        void* args[] = {(void*)&A, (void*)&x, (void*)&Wheads, (void*)&aheads,
                        (void*)&Wout, (void*)&aout,
                        (void*)&nbr, (void*)&cnt, (void*)&Wh, (void*)&es, (void*)&ed,
                        (void*)&Wh2, (void*)&es2, (void*)&ed2, (void*)&zh, (void*)&zl,
                        (void*)&out};
        le = hipLaunchCooperativeKernel((void*)k_mega, dim3(gridB), dim3(256), args, 0, stream);
    }
    if (le != hipSuccess) {
        k_pre     <<<GEMM_BLOCKS + NN, 256, 0, stream>>>(A, x, Wheads, aheads, nbr, cnt, Wh, es, ed);
        k_attn1g2 <<<NN, 256, 0, stream>>>(nbr, cnt, es, ed, Wh, Wout, aout, Wh2, es2, ed2);
        k_attn2   <<<NN / 4, 256, 0, stream>>>(nbr, cnt, es2, ed2, Wh2, zh, zl);
        k_zzt     <<<ZTILES, 256, 0, stream>>>(zh, zl, out);
    }
}

// Round 7
// 115.929 us; speedup vs baseline: 4.4586x; 4.4586x over previous
//
#include <hip/hip_runtime.h>
#include <hip/hip_bf16.h>

#define NN 6144
#define IN_DIM 256
#define HID 64
#define HEADS 4
#define LAT 32
#define CAP 192
#define ALPHA 0.2f
#define GEMM_BLOCKS 384                  // (NN/64) * HEADS
#define ZTILES ((NN / 64) * (NN / 64))   // 9216

typedef __attribute__((ext_vector_type(8))) short bf16x8;
typedef __attribute__((ext_vector_type(4))) float f32x4;

__device__ __forceinline__ float elu_f(float v)   { return v > 0.f ? v : expm1f(v); }
__device__ __forceinline__ float lrelu_f(float v) { return v > 0.f ? v : ALPHA * v; }

__device__ __forceinline__ void split_bf16(float v, unsigned short& hi, unsigned short& lo) {
    unsigned u = __builtin_bit_cast(unsigned, v);
    hi = (unsigned short)(u >> 16);
    float vh = __builtin_bit_cast(float, u & 0xFFFF0000u);
    float rl = v - vh;                       // exact
    lo = (unsigned short)(__builtin_bit_cast(unsigned, rl) >> 16);
}

// ---------------- k_pre: gemm1(+es/ed epilogue) blocks first, then A-scan blocks ----------------
__global__ __launch_bounds__(256) void k_pre(const float* __restrict__ A,
                                             const float* __restrict__ x,
                                             const float* __restrict__ Wheads,
                                             const float* __restrict__ aheads,
                                             int* __restrict__ nbr, int* __restrict__ cnt,
                                             float* __restrict__ Wh,
                                             float* __restrict__ es, float* __restrict__ ed) {
    __shared__ __align__(16) float smem[2048];   // 8 KB
    int bid = blockIdx.x;
    int t = threadIdx.x;
    if (bid < GEMM_BLOCKS) {
        int head = bid & 3, m0 = (bid >> 2) * 64;
        float (*As)[64] = (float(*)[64])smem;
        float (*Bs)[64] = (float(*)[64])(smem + 1024);
        const float* Wc = Wheads + (size_t)head * IN_DIM * HID;
        int ty = t >> 4, tx = t & 15;
        float acc[4][4] = {};
        for (int k0 = 0; k0 < IN_DIM; k0 += 16) {
            {
                int row = t >> 2, k4 = (t & 3) * 4;
                float4 v = *(const float4*)(x + (size_t)(m0 + row) * IN_DIM + k0 + k4);
                As[k4 + 0][row] = v.x; As[k4 + 1][row] = v.y;
                As[k4 + 2][row] = v.z; As[k4 + 3][row] = v.w;
                int kk = t >> 4, n4 = (t & 15) * 4;
                *(float4*)&Bs[kk][n4] = *(const float4*)(Wc + (size_t)(k0 + kk) * HID + n4);
            }
            __syncthreads();
            #pragma unroll
            for (int k = 0; k < 16; ++k) {
                float4 av = *(float4*)&As[k][ty * 4];
                float4 bv = *(float4*)&Bs[k][tx * 4];
                float ar[4] = {av.x, av.y, av.z, av.w};
                float br[4] = {bv.x, bv.y, bv.z, bv.w};
                #pragma unroll
                for (int i = 0; i < 4; ++i)
                    #pragma unroll
                    for (int j = 0; j < 4; ++j)
                        acc[i][j] = fmaf(ar[i], br[j], acc[i][j]);
            }
            __syncthreads();
        }
        #pragma unroll
        for (int i = 0; i < 4; ++i) {
            float4 o = make_float4(acc[i][0], acc[i][1], acc[i][2], acc[i][3]);
            *(float4*)(Wh + (size_t)(m0 + ty * 4 + i) * (HEADS * HID) + head * HID + tx * 4) = o;
        }
        float4 a1v = *(const float4*)(aheads + head * 2 * HID + tx * 4);
        float4 a2v = *(const float4*)(aheads + head * 2 * HID + HID + tx * 4);
        #pragma unroll
        for (int i = 0; i < 4; ++i) {
            float p1 = acc[i][0] * a1v.x + acc[i][1] * a1v.y + acc[i][2] * a1v.z + acc[i][3] * a1v.w;
            float p2 = acc[i][0] * a2v.x + acc[i][1] * a2v.y + acc[i][2] * a2v.z + acc[i][3] * a2v.w;
            #pragma unroll
            for (int off = 8; off; off >>= 1) {
                p1 += __shfl_down(p1, off, 16);
                p2 += __shfl_down(p2, off, 16);
            }
            if (tx == 0) {
                es[head * NN + m0 + ty * 4 + i] = p1;
                ed[head * NN + m0 + ty * 4 + i] = p2;
            }
        }
    } else {
        int row = bid - GEMM_BLOCKS;
        int* lcnt = (int*)smem;
        const float4* Arow = (const float4*)(A + (size_t)row * NN);
        if (t == 0) *lcnt = 0;
        __syncthreads();
        int* my = nbr + (size_t)row * CAP;
        #pragma unroll
        for (int it = 0; it < NN / 4 / 256; ++it) {
            int idx4 = it * 256 + t;
            float4 v = Arow[idx4];
            int base = idx4 * 4;
            if (v.x != 0.f) { int p = atomicAdd(lcnt, 1); if (p < CAP) my[p] = base; }
            if (v.y != 0.f) { int p = atomicAdd(lcnt, 1); if (p < CAP) my[p] = base + 1; }
            if (v.z != 0.f) { int p = atomicAdd(lcnt, 1); if (p < CAP) my[p] = base + 2; }
            if (v.w != 0.f) { int p = atomicAdd(lcnt, 1); if (p < CAP) my[p] = base + 3; }
        }
        __syncthreads();
        if (t == 0) cnt[row] = *lcnt < CAP ? *lcnt : CAP;
    }
}

// ---------------- k_attn1g2: attention layer 1 (4 waves = 4 heads per row) + fused gemm2/e2 ----------------
__global__ __launch_bounds__(256) void k_attn1g2(const int* __restrict__ nbr, const int* __restrict__ cnt,
                                                 const float* __restrict__ es, const float* __restrict__ ed,
                                                 const float* __restrict__ Wh,
                                                 const float* __restrict__ Wout, const float* __restrict__ aout,
                                                 float* __restrict__ Wh2,
                                                 float* __restrict__ es2, float* __restrict__ ed2) {
    __shared__ int col[CAP];
    __shared__ float att[HEADS][CAP];
    __shared__ float hrow[HEADS * HID];
    __shared__ float part[8][LAT];
    int i = blockIdx.x;
    int t = threadIdx.x, h = t >> 6, l = t & 63;
    int c = cnt[i];
    float hval;
    if (c == 0) {
        float s = 0.f;
        for (int r = 0; r < NN; ++r) s += Wh[(size_t)r * (HEADS * HID) + h * HID + l];
        hval = elu_f(s * (1.0f / NN));
    } else {
        const int* nb = nbr + (size_t)i * CAP;
        float esi = es[h * NN + i];
        float m = -3.0e38f;
        for (int j = l; j < c; j += 64) {
            int cj = nb[j];
            if (h == 0) col[j] = cj;
            float e = lrelu_f(esi + ed[h * NN + cj]);
            att[h][j] = e;
            m = fmaxf(m, e);
        }
        #pragma unroll
        for (int off = 32; off; off >>= 1) m = fmaxf(m, __shfl_down(m, off));
        m = __shfl(m, 0);
        float s = 0.f;
        for (int j = l; j < c; j += 64) {
            float p = __expf(att[h][j] - m);
            att[h][j] = p;
            s += p;
        }
        #pragma unroll
        for (int off = 32; off; off >>= 1) s += __shfl_down(s, off);
        s = __shfl(s, 0);
        __syncthreads();          // col[] + att[h][] visible to all
        float inv = 1.0f / s;
        const float* WhH = Wh + h * HID + l;
        float a0 = 0.f, a1 = 0.f, a2 = 0.f, a3 = 0.f;
        float a4 = 0.f, a5 = 0.f, a6 = 0.f, a7 = 0.f;
        int j = 0;
        for (; j + 8 <= c; j += 8) {
            a0 = fmaf(att[h][j + 0], WhH[(size_t)col[j + 0] * (HEADS * HID)], a0);
            a1 = fmaf(att[h][j + 1], WhH[(size_t)col[j + 1] * (HEADS * HID)], a1);
            a2 = fmaf(att[h][j + 2], WhH[(size_t)col[j + 2] * (HEADS * HID)], a2);
            a3 = fmaf(att[h][j + 3], WhH[(size_t)col[j + 3] * (HEADS * HID)], a3);
            a4 = fmaf(att[h][j + 4], WhH[(size_t)col[j + 4] * (HEADS * HID)], a4);
            a5 = fmaf(att[h][j + 5], WhH[(size_t)col[j + 5] * (HEADS * HID)], a5);
            a6 = fmaf(att[h][j + 6], WhH[(size_t)col[j + 6] * (HEADS * HID)], a6);
            a7 = fmaf(att[h][j + 7], WhH[(size_t)col[j + 7] * (HEADS * HID)], a7);
        }
        for (; j < c; ++j)
            a0 = fmaf(att[h][j], WhH[(size_t)col[j] * (HEADS * HID)], a0);
        hval = elu_f((((a0 + a1) + (a2 + a3)) + ((a4 + a5) + (a6 + a7))) * inv);
    }
    hrow[h * HID + l] = hval;
    __syncthreads();
    {
        int half = l >> 5, cc = l & 31;
        int tbase = h * HID + half * 32;
        float p = 0.f;
        #pragma unroll 8
        for (int tt = 0; tt < 32; ++tt)
            p = fmaf(hrow[tbase + tt], Wout[(tbase + tt) * LAT + cc], p);
        part[h * 2 + half][cc] = p;
    }
    __syncthreads();
    if (t < 32) {
        float acc = 0.f;
        #pragma unroll
        for (int w = 0; w < 8; ++w) acc += part[w][t];
        Wh2[(size_t)i * LAT + t] = acc;
        float p1 = acc * aout[t], p2 = acc * aout[LAT + t];
        #pragma unroll
        for (int off = 16; off; off >>= 1) {
            p1 += __shfl_down(p1, off, 32);
            p2 += __shfl_down(p2, off, 32);
        }
        if (t == 0) { es2[i] = p1; ed2[i] = p2; }
    }
}

// ---------------- attention layer 2 -> z (split bf16 out), 4 rows per block ----------------
__global__ __launch_bounds__(256) void k_attn2(const int* __restrict__ nbr, const int* __restrict__ cnt,
                                               const float* __restrict__ es2, const float* __restrict__ ed2,
                                               const float* __restrict__ Wh2,
                                               unsigned short* __restrict__ zh, unsigned short* __restrict__ zl) {
    __shared__ float att[4][CAP];
    __shared__ int col[4][CAP];
    int w = threadIdx.x >> 6, l = threadIdx.x & 63;
    int i = blockIdx.x * 4 + w;
    int c = cnt[i];
    if (c == 0) {
        if (l < LAT) {
            float s = 0.f;
            for (int r = 0; r < NN; ++r) s += Wh2[(size_t)r * LAT + l];
            unsigned short hi, lo;
            split_bf16(elu_f(s * (1.0f / NN)), hi, lo);
            zh[(size_t)i * LAT + l] = hi;
            zl[(size_t)i * LAT + l] = lo;
        }
        return;
    }
    float esi = es2[i];
    const int* nb = nbr + (size_t)i * CAP;
    float m = -3.0e38f;
    for (int j = l; j < c; j += 64) {
        int cj = nb[j];
        col[w][j] = cj;
        float e = lrelu_f(esi + ed2[cj]);
        att[w][j] = e;
        m = fmaxf(m, e);
    }
    #pragma unroll
    for (int off = 32; off; off >>= 1) m = fmaxf(m, __shfl_down(m, off));
    m = __shfl(m, 0);
    float s = 0.f;
    for (int j = l; j < c; j += 64) {
        float p = __expf(att[w][j] - m);
        att[w][j] = p;
        s += p;
    }
    #pragma unroll
    for (int off = 32; off; off >>= 1) s += __shfl_down(s, off);
    s = __shfl(s, 0);
    if (l < LAT) {
        float inv = 1.0f / s;
        float a0 = 0.f, a1 = 0.f, a2 = 0.f, a3 = 0.f;
        int j = 0;
        for (; j + 4 <= c; j += 4) {
            a0 = fmaf(att[w][j + 0], Wh2[(size_t)col[w][j + 0] * LAT + l], a0);
            a1 = fmaf(att[w][j + 1], Wh2[(size_t)col[w][j + 1] * LAT + l], a1);
            a2 = fmaf(att[w][j + 2], Wh2[(size_t)col[w][j + 2] * LAT + l], a2);
            a3 = fmaf(att[w][j + 3], Wh2[(size_t)col[w][j + 3] * LAT + l], a3);
        }
        for (; j < c; ++j)
            a0 = fmaf(att[w][j], Wh2[(size_t)col[w][j] * LAT + l], a0);
        unsigned short hi, lo;
        split_bf16(elu_f(((a0 + a1) + (a2 + a3)) * inv), hi, lo);
        zh[(size_t)i * LAT + l] = hi;
        zl[(size_t)i * LAT + l] = lo;
    }
}

// ---------------- out = sigmoid(z @ z^T) via split-bf16 MFMA, no LDS ----------------
__global__ __launch_bounds__(256) void k_zzt(const unsigned short* __restrict__ zh,
                                             const unsigned short* __restrict__ zl,
                                             float* __restrict__ out) {
    int t = threadIdx.x, w = t >> 6, l = t & 63;
    int m0 = blockIdx.y * 64 + w * 16;
    int n0 = blockIdx.x * 64;
    int r = l & 15, kg = (l >> 4) * 8;   // lane row-in-tile, k-group of 8
    bf16x8 ah = *(const bf16x8*)(zh + (size_t)(m0 + r) * LAT + kg);
    bf16x8 al = *(const bf16x8*)(zl + (size_t)(m0 + r) * LAT + kg);
    // preload ALL B fragments so the 10 global loads are in flight before MFMAs wait on them
    bf16x8 bh[4], bl[4];
    #pragma unroll
    for (int j = 0; j < 4; ++j) {
        int nb = n0 + j * 16;
        bh[j] = *(const bf16x8*)(zh + (size_t)(nb + r) * LAT + kg);
        bl[j] = *(const bf16x8*)(zl + (size_t)(nb + r) * LAT + kg);
    }
    #pragma unroll
    for (int j = 0; j < 4; ++j) {
        f32x4 acc = {0.f, 0.f, 0.f, 0.f};
        acc = __builtin_amdgcn_mfma_f32_16x16x32_bf16(ah, bh[j], acc, 0, 0, 0);
        acc = __builtin_amdgcn_mfma_f32_16x16x32_bf16(ah, bl[j], acc, 0, 0, 0);
        acc = __builtin_amdgcn_mfma_f32_16x16x32_bf16(al, bh[j], acc, 0, 0, 0);
        #pragma unroll
        for (int rr = 0; rr < 4; ++rr) {
            int row = m0 + (l >> 4) * 4 + rr;
            int colo = n0 + j * 16 + (l & 15);
            out[(size_t)row * NN + colo] = 1.0f / (1.0f + __expf(-acc[rr]));
        }
    }
}

extern "C" void kernel_launch(void* const* d_in, const int* in_sizes, int n_in,
                              void* d_out, int out_size, void* d_ws, size_t ws_size,
                              hipStream_t stream) {
    const float* x      = (const float*)d_in[0];
    const float* A      = (const float*)d_in[1];
    const float* Wheads = (const float*)d_in[2];
    const float* aheads = (const float*)d_in[3];
    const float* Wout   = (const float*)d_in[4];
    const float* aout   = (const float*)d_in[5];
    float* out = (float*)d_out;

    char* ws = (char*)d_ws;
    size_t o = 0;
    auto alloc = [&](size_t bytes) { void* p = ws + o; o += (bytes + 255) & ~(size_t)255; return p; };
    int*   nbr   = (int*)  alloc((size_t)NN * CAP * 4);
    int*   cnt   = (int*)  alloc((size_t)NN * 4);
    float* Wh    = (float*)alloc((size_t)NN * HEADS * HID * 4);
    float* es    = (float*)alloc((size_t)HEADS * NN * 4);
    float* ed    = (float*)alloc((size_t)HEADS * NN * 4);
    float* Wh2   = (float*)alloc((size_t)NN * LAT * 4);
    float* es2   = (float*)alloc((size_t)NN * 4);
    float* ed2   = (float*)alloc((size_t)NN * 4);
    unsigned short* zh = (unsigned short*)alloc((size_t)NN * LAT * 2);
    unsigned short* zl = (unsigned short*)alloc((size_t)NN * LAT * 2);

    k_pre     <<<GEMM_BLOCKS + NN, 256, 0, stream>>>(A, x, Wheads, aheads, nbr, cnt, Wh, es, ed);
    k_attn1g2 <<<NN, 256, 0, stream>>>(nbr, cnt, es, ed, Wh, Wout, aout, Wh2, es2, ed2);
    k_attn2   <<<NN / 4, 256, 0, stream>>>(nbr, cnt, es2, ed2, Wh2, zh, zl);
    k_zzt     <<<dim3(NN / 64, NN / 64), 256, 0, stream>>>(zh, zl, out);
}

// Round 8
// 115.608 us; speedup vs baseline: 4.4711x; 1.0028x over previous
//
#include <hip/hip_runtime.h>
#include <hip/hip_bf16.h>

#define NN 6144
#define IN_DIM 256
#define HID 64
#define HEADS 4
#define LAT 32
#define CAP 192
#define ALPHA 0.2f
#define GEMM_BLOCKS 384                  // (NN/64) * HEADS

typedef __attribute__((ext_vector_type(8))) short bf16x8;
typedef __attribute__((ext_vector_type(4))) float f32x4;

__device__ __forceinline__ float elu_f(float v)   { return v > 0.f ? v : expm1f(v); }
__device__ __forceinline__ float lrelu_f(float v) { return v > 0.f ? v : ALPHA * v; }

__device__ __forceinline__ void split_bf16(float v, unsigned short& hi, unsigned short& lo) {
    unsigned u = __builtin_bit_cast(unsigned, v);
    hi = (unsigned short)(u >> 16);
    float vh = __builtin_bit_cast(float, u & 0xFFFF0000u);
    float rl = v - vh;                       // exact
    lo = (unsigned short)(__builtin_bit_cast(unsigned, rl) >> 16);
}

// ---------------- k_pre: gemm1(+es/ed epilogue) blocks first, then A-scan blocks ----------------
__global__ __launch_bounds__(256) void k_pre(const float* __restrict__ A,
                                             const float* __restrict__ x,
                                             const float* __restrict__ Wheads,
                                             const float* __restrict__ aheads,
                                             int* __restrict__ nbr, int* __restrict__ cnt,
                                             float* __restrict__ Wh,
                                             float* __restrict__ es, float* __restrict__ ed) {
    __shared__ __align__(16) float smem[2048];   // 8 KB
    int bid = blockIdx.x;
    int t = threadIdx.x;
    if (bid < GEMM_BLOCKS) {
        int head = bid & 3, m0 = (bid >> 2) * 64;
        float (*As)[64] = (float(*)[64])smem;
        float (*Bs)[64] = (float(*)[64])(smem + 1024);
        const float* Wc = Wheads + (size_t)head * IN_DIM * HID;
        int ty = t >> 4, tx = t & 15;
        float acc[4][4] = {};
        for (int k0 = 0; k0 < IN_DIM; k0 += 16) {
            {
                int row = t >> 2, k4 = (t & 3) * 4;
                float4 v = *(const float4*)(x + (size_t)(m0 + row) * IN_DIM + k0 + k4);
                As[k4 + 0][row] = v.x; As[k4 + 1][row] = v.y;
                As[k4 + 2][row] = v.z; As[k4 + 3][row] = v.w;
                int kk = t >> 4, n4 = (t & 15) * 4;
                *(float4*)&Bs[kk][n4] = *(const float4*)(Wc + (size_t)(k0 + kk) * HID + n4);
            }
            __syncthreads();
            #pragma unroll
            for (int k = 0; k < 16; ++k) {
                float4 av = *(float4*)&As[k][ty * 4];
                float4 bv = *(float4*)&Bs[k][tx * 4];
                float ar[4] = {av.x, av.y, av.z, av.w};
                float br[4] = {bv.x, bv.y, bv.z, bv.w};
                #pragma unroll
                for (int i = 0; i < 4; ++i)
                    #pragma unroll
                    for (int j = 0; j < 4; ++j)
                        acc[i][j] = fmaf(ar[i], br[j], acc[i][j]);
            }
            __syncthreads();
        }
        #pragma unroll
        for (int i = 0; i < 4; ++i) {
            float4 o = make_float4(acc[i][0], acc[i][1], acc[i][2], acc[i][3]);
            *(float4*)(Wh + (size_t)(m0 + ty * 4 + i) * (HEADS * HID) + head * HID + tx * 4) = o;
        }
        float4 a1v = *(const float4*)(aheads + head * 2 * HID + tx * 4);
        float4 a2v = *(const float4*)(aheads + head * 2 * HID + HID + tx * 4);
        #pragma unroll
        for (int i = 0; i < 4; ++i) {
            float p1 = acc[i][0] * a1v.x + acc[i][1] * a1v.y + acc[i][2] * a1v.z + acc[i][3] * a1v.w;
            float p2 = acc[i][0] * a2v.x + acc[i][1] * a2v.y + acc[i][2] * a2v.z + acc[i][3] * a2v.w;
            #pragma unroll
            for (int off = 8; off; off >>= 1) {
                p1 += __shfl_down(p1, off, 16);
                p2 += __shfl_down(p2, off, 16);
            }
            if (tx == 0) {
                es[head * NN + m0 + ty * 4 + i] = p1;
                ed[head * NN + m0 + ty * 4 + i] = p2;
            }
        }
    } else {
        int row = bid - GEMM_BLOCKS;
        int* lcnt = (int*)smem;
        const float4* Arow = (const float4*)(A + (size_t)row * NN);
        if (t == 0) *lcnt = 0;
        __syncthreads();
        int* my = nbr + (size_t)row * CAP;
        #pragma unroll
        for (int it = 0; it < NN / 4 / 256; ++it) {
            int idx4 = it * 256 + t;
            float4 v = Arow[idx4];
            int base = idx4 * 4;
            if (v.x != 0.f) { int p = atomicAdd(lcnt, 1); if (p < CAP) my[p] = base; }
            if (v.y != 0.f) { int p = atomicAdd(lcnt, 1); if (p < CAP) my[p] = base + 1; }
            if (v.z != 0.f) { int p = atomicAdd(lcnt, 1); if (p < CAP) my[p] = base + 2; }
            if (v.w != 0.f) { int p = atomicAdd(lcnt, 1); if (p < CAP) my[p] = base + 3; }
        }
        __syncthreads();
        if (t == 0) cnt[row] = *lcnt < CAP ? *lcnt : CAP;
    }
}

// ---------------- k_attn1g2: attention layer 1 (4 waves = 4 heads per row) + fused gemm2/e2 ----------------
// __launch_bounds__(256, 8): cap VGPR at 64 -> 8 blocks/CU to hide PV gather latency
__global__ __launch_bounds__(256, 8) void k_attn1g2(const int* __restrict__ nbr, const int* __restrict__ cnt,
                                                    const float* __restrict__ es, const float* __restrict__ ed,
                                                    const float* __restrict__ Wh,
                                                    const float* __restrict__ Wout, const float* __restrict__ aout,
                                                    float* __restrict__ Wh2,
                                                    float* __restrict__ es2, float* __restrict__ ed2) {
    __shared__ int col[CAP];
    __shared__ float att[HEADS][CAP];
    __shared__ float hrow[HEADS * HID];
    __shared__ float part[8][LAT];
    int i = blockIdx.x;
    int t = threadIdx.x, h = t >> 6, l = t & 63;
    int c = cnt[i];
    float hval;
    if (c == 0) {
        float s = 0.f;
        for (int r = 0; r < NN; ++r) s += Wh[(size_t)r * (HEADS * HID) + h * HID + l];
        hval = elu_f(s * (1.0f / NN));
    } else {
        const int* nb = nbr + (size_t)i * CAP;
        float esi = es[h * NN + i];
        float m = -3.0e38f;
        for (int j = l; j < c; j += 64) {
            int cj = nb[j];
            if (h == 0) col[j] = cj;
            float e = lrelu_f(esi + ed[h * NN + cj]);
            att[h][j] = e;
            m = fmaxf(m, e);
        }
        #pragma unroll
        for (int off = 32; off; off >>= 1) m = fmaxf(m, __shfl_down(m, off));
        m = __shfl(m, 0);
        float s = 0.f;
        for (int j = l; j < c; j += 64) {
            float p = __expf(att[h][j] - m);
            att[h][j] = p;
            s += p;
        }
        #pragma unroll
        for (int off = 32; off; off >>= 1) s += __shfl_down(s, off);
        s = __shfl(s, 0);
        __syncthreads();          // col[] + att[h][] visible to all
        float inv = 1.0f / s;
        const float* WhH = Wh + h * HID + l;
        float a0 = 0.f, a1 = 0.f, a2 = 0.f, a3 = 0.f;
        float a4 = 0.f, a5 = 0.f, a6 = 0.f, a7 = 0.f;
        int j = 0;
        for (; j + 8 <= c; j += 8) {
            a0 = fmaf(att[h][j + 0], WhH[(size_t)col[j + 0] * (HEADS * HID)], a0);
            a1 = fmaf(att[h][j + 1], WhH[(size_t)col[j + 1] * (HEADS * HID)], a1);
            a2 = fmaf(att[h][j + 2], WhH[(size_t)col[j + 2] * (HEADS * HID)], a2);
            a3 = fmaf(att[h][j + 3], WhH[(size_t)col[j + 3] * (HEADS * HID)], a3);
            a4 = fmaf(att[h][j + 4], WhH[(size_t)col[j + 4] * (HEADS * HID)], a4);
            a5 = fmaf(att[h][j + 5], WhH[(size_t)col[j + 5] * (HEADS * HID)], a5);
            a6 = fmaf(att[h][j + 6], WhH[(size_t)col[j + 6] * (HEADS * HID)], a6);
            a7 = fmaf(att[h][j + 7], WhH[(size_t)col[j + 7] * (HEADS * HID)], a7);
        }
        for (; j < c; ++j)
            a0 = fmaf(att[h][j], WhH[(size_t)col[j] * (HEADS * HID)], a0);
        hval = elu_f((((a0 + a1) + (a2 + a3)) + ((a4 + a5) + (a6 + a7))) * inv);
    }
    hrow[h * HID + l] = hval;
    __syncthreads();
    {
        int half = l >> 5, cc = l & 31;
        int tbase = h * HID + half * 32;
        float p = 0.f;
        #pragma unroll 8
        for (int tt = 0; tt < 32; ++tt)
            p = fmaf(hrow[tbase + tt], Wout[(tbase + tt) * LAT + cc], p);
        part[h * 2 + half][cc] = p;
    }
    __syncthreads();
    if (t < 32) {
        float acc = 0.f;
        #pragma unroll
        for (int w = 0; w < 8; ++w) acc += part[w][t];
        Wh2[(size_t)i * LAT + t] = acc;
        float p1 = acc * aout[t], p2 = acc * aout[LAT + t];
        #pragma unroll
        for (int off = 16; off; off >>= 1) {
            p1 += __shfl_down(p1, off, 32);
            p2 += __shfl_down(p2, off, 32);
        }
        if (t == 0) { es2[i] = p1; ed2[i] = p2; }
    }
}

// ---------------- attention layer 2 -> z (split bf16 out), 4 rows per block ----------------
__global__ __launch_bounds__(256, 8) void k_attn2(const int* __restrict__ nbr, const int* __restrict__ cnt,
                                                  const float* __restrict__ es2, const float* __restrict__ ed2,
                                                  const float* __restrict__ Wh2,
                                                  unsigned short* __restrict__ zh, unsigned short* __restrict__ zl) {
    __shared__ float att[4][CAP];
    __shared__ int col[4][CAP];
    int w = threadIdx.x >> 6, l = threadIdx.x & 63;
    int i = blockIdx.x * 4 + w;
    int c = cnt[i];
    if (c == 0) {
        if (l < LAT) {
            float s = 0.f;
            for (int r = 0; r < NN; ++r) s += Wh2[(size_t)r * LAT + l];
            unsigned short hi, lo;
            split_bf16(elu_f(s * (1.0f / NN)), hi, lo);
            zh[(size_t)i * LAT + l] = hi;
            zl[(size_t)i * LAT + l] = lo;
        }
        return;
    }
    float esi = es2[i];
    const int* nb = nbr + (size_t)i * CAP;
    float m = -3.0e38f;
    for (int j = l; j < c; j += 64) {
        int cj = nb[j];
        col[w][j] = cj;
        float e = lrelu_f(esi + ed2[cj]);
        att[w][j] = e;
        m = fmaxf(m, e);
    }
    #pragma unroll
    for (int off = 32; off; off >>= 1) m = fmaxf(m, __shfl_down(m, off));
    m = __shfl(m, 0);
    float s = 0.f;
    for (int j = l; j < c; j += 64) {
        float p = __expf(att[w][j] - m);
        att[w][j] = p;
        s += p;
    }
    #pragma unroll
    for (int off = 32; off; off >>= 1) s += __shfl_down(s, off);
    s = __shfl(s, 0);
    if (l < LAT) {
        float inv = 1.0f / s;
        float a0 = 0.f, a1 = 0.f, a2 = 0.f, a3 = 0.f;
        int j = 0;
        for (; j + 4 <= c; j += 4) {
            a0 = fmaf(att[w][j + 0], Wh2[(size_t)col[w][j + 0] * LAT + l], a0);
            a1 = fmaf(att[w][j + 1], Wh2[(size_t)col[w][j + 1] * LAT + l], a1);
            a2 = fmaf(att[w][j + 2], Wh2[(size_t)col[w][j + 2] * LAT + l], a2);
            a3 = fmaf(att[w][j + 3], Wh2[(size_t)col[w][j + 3] * LAT + l], a3);
        }
        for (; j < c; ++j)
            a0 = fmaf(att[w][j], Wh2[(size_t)col[w][j] * LAT + l], a0);
        unsigned short hi, lo;
        split_bf16(elu_f(((a0 + a1) + (a2 + a3)) * inv), hi, lo);
        zh[(size_t)i * LAT + l] = hi;
        zl[(size_t)i * LAT + l] = lo;
    }
}

// ---------------- out = sigmoid(z @ z^T) via split-bf16 MFMA, no LDS ----------------
// __launch_bounds__(256, 8): <=64 VGPR -> 8 blocks/CU for more outstanding stores.
// B fragments preloaded 2 tiles ahead (16 regs in flight) instead of 4 (32 regs).
__global__ __launch_bounds__(256, 8) void k_zzt(const unsigned short* __restrict__ zh,
                                                const unsigned short* __restrict__ zl,
                                                float* __restrict__ out) {
    int t = threadIdx.x, w = t >> 6, l = t & 63;
    int m0 = blockIdx.y * 64 + w * 16;
    int n0 = blockIdx.x * 64;
    int r = l & 15, kg = (l >> 4) * 8;   // lane row-in-tile, k-group of 8
    bf16x8 ah = *(const bf16x8*)(zh + (size_t)(m0 + r) * LAT + kg);
    bf16x8 al = *(const bf16x8*)(zl + (size_t)(m0 + r) * LAT + kg);
    #pragma unroll
    for (int jp = 0; jp < 2; ++jp) {
        int nbA = n0 + (jp * 2 + 0) * 16;
        int nbB = n0 + (jp * 2 + 1) * 16;
        bf16x8 bhA = *(const bf16x8*)(zh + (size_t)(nbA + r) * LAT + kg);
        bf16x8 blA = *(const bf16x8*)(zl + (size_t)(nbA + r) * LAT + kg);
        bf16x8 bhB = *(const bf16x8*)(zh + (size_t)(nbB + r) * LAT + kg);
        bf16x8 blB = *(const bf16x8*)(zl + (size_t)(nbB + r) * LAT + kg);
        f32x4 accA = {0.f, 0.f, 0.f, 0.f};
        accA = __builtin_amdgcn_mfma_f32_16x16x32_bf16(ah, bhA, accA, 0, 0, 0);
        accA = __builtin_amdgcn_mfma_f32_16x16x32_bf16(ah, blA, accA, 0, 0, 0);
        accA = __builtin_amdgcn_mfma_f32_16x16x32_bf16(al, bhA, accA, 0, 0, 0);
        f32x4 accB = {0.f, 0.f, 0.f, 0.f};
        accB = __builtin_amdgcn_mfma_f32_16x16x32_bf16(ah, bhB, accB, 0, 0, 0);
        accB = __builtin_amdgcn_mfma_f32_16x16x32_bf16(ah, blB, accB, 0, 0, 0);
        accB = __builtin_amdgcn_mfma_f32_16x16x32_bf16(al, bhB, accB, 0, 0, 0);
        #pragma unroll
        for (int rr = 0; rr < 4; ++rr) {
            int row = m0 + (l >> 4) * 4 + rr;
            out[(size_t)row * NN + nbA + (l & 15)] = 1.0f / (1.0f + __expf(-accA[rr]));
            out[(size_t)row * NN + nbB + (l & 15)] = 1.0f / (1.0f + __expf(-accB[rr]));
        }
    }
}

extern "C" void kernel_launch(void* const* d_in, const int* in_sizes, int n_in,
                              void* d_out, int out_size, void* d_ws, size_t ws_size,
                              hipStream_t stream) {
    const float* x      = (const float*)d_in[0];
    const float* A      = (const float*)d_in[1];
    const float* Wheads = (const float*)d_in[2];
    const float* aheads = (const float*)d_in[3];
    const float* Wout   = (const float*)d_in[4];
    const float* aout   = (const float*)d_in[5];
    float* out = (float*)d_out;

    char* ws = (char*)d_ws;
    size_t o = 0;
    auto alloc = [&](size_t bytes) { void* p = ws + o; o += (bytes + 255) & ~(size_t)255; return p; };
    int*   nbr   = (int*)  alloc((size_t)NN * CAP * 4);
    int*   cnt   = (int*)  alloc((size_t)NN * 4);
    float* Wh    = (float*)alloc((size_t)NN * HEADS * HID * 4);
    float* es    = (float*)alloc((size_t)HEADS * NN * 4);
    float* ed    = (float*)alloc((size_t)HEADS * NN * 4);
    float* Wh2   = (float*)alloc((size_t)NN * LAT * 4);
    float* es2   = (float*)alloc((size_t)NN * 4);
    float* ed2   = (float*)alloc((size_t)NN * 4);
    unsigned short* zh = (unsigned short*)alloc((size_t)NN * LAT * 2);
    unsigned short* zl = (unsigned short*)alloc((size_t)NN * LAT * 2);

    k_pre     <<<GEMM_BLOCKS + NN, 256, 0, stream>>>(A, x, Wheads, aheads, nbr, cnt, Wh, es, ed);
    k_attn1g2 <<<NN, 256, 0, stream>>>(nbr, cnt, es, ed, Wh, Wout, aout, Wh2, es2, ed2);
    k_attn2   <<<NN / 4, 256, 0, stream>>>(nbr, cnt, es2, ed2, Wh2, zh, zl);
    k_zzt     <<<dim3(NN / 64, NN / 64), 256, 0, stream>>>(zh, zl, out);
}